// Round 10
// baseline (4261.386 us; speedup 1.0000x reference)
//
#include <hip/hip_runtime.h>
#include <stdint.h>

#define NB 16
#define HH 128
#define WW 128
#define L (HH*WW)        // 16384
#define CIN 3
#define HID 256
#define NC 21
#define CHUNK 256
#define WARM 512
#define NCHUNKS (L/CHUNK)   // 64
#define T_PER 32            // t's per wave in k_bp
#define NPACK (L/4)         // 4096 packs of 4 timesteps

// ---------------- K1: conv -> fp32 emissions, stored TRANSPOSED em_T[b][c][t] ----------------
// fp64 accumulate (round once to fp32 = correctly rounded), fp32 elementwise bias in ref order.
__global__ __launch_bounds__(256) void k_conv(
    const float* __restrict__ x, const float* __restrict__ w1,
    const float* __restrict__ b1, const float* __restrict__ w2,
    const float* __restrict__ b2, float* __restrict__ emT)
{
    int tid = threadIdx.x;
    int g  = blockIdx.x * 256 + tid;      // 0..B*L-1
    int b  = g >> 14;
    int t  = g & (L-1);
    int y  = t >> 7;
    int xx = t & (WW-1);

    double p[27];
    const float* xb = x + (size_t)b * CIN * L;
    #pragma unroll
    for (int ic = 0; ic < CIN; ++ic) {
        #pragma unroll
        for (int ky = 0; ky < 3; ++ky) {
            #pragma unroll
            for (int kx = 0; kx < 3; ++kx) {
                int yy = y + ky - 1, xc = xx + kx - 1;
                float v = 0.f;
                if (yy >= 0 && yy < HH && xc >= 0 && xc < WW)
                    v = xb[ic * L + yy * WW + xc];
                p[ic*9 + ky*3 + kx] = (double)v;
            }
        }
    }

    double acc[NC];
    #pragma unroll
    for (int c = 0; c < NC; ++c) acc[c] = 0.0;

    // unroll 2: pipelines the wave-uniform (scalar) weight loads behind fp64 FMAs.
    // Per-accumulator FP op order is unchanged -> bit-identical results.
    #pragma unroll 2
    for (int oc = 0; oc < HID; ++oc) {
        double hv = 0.0;                              // conv1 accum
        #pragma unroll
        for (int j = 0; j < 27; ++j) hv += (double)w1[oc*27 + j] * p[j];
        float h32 = (float)hv;                        // round conv1 to fp32
        h32 = h32 + b1[oc];                           // fp32 elementwise bias
        h32 = fmaxf(h32, 0.f);                        // relu (fp32)
        double hd = (double)h32;
        #pragma unroll
        for (int c = 0; c < NC; ++c) acc[c] += (double)w2[c*HID + oc] * hd;
    }
    float* dstb = emT + (size_t)b * NC * L;
    #pragma unroll
    for (int c = 0; c < NC; ++c) {
        float e32 = (float)acc[c];                    // round conv2 to fp32
        dstb[(size_t)c * L + t] = e32 + b2[c];        // transposed store (coalesced in t)
    }
}

// ---------------- K2a: sequential fp32 score recursion, LDS broadcast, 2 chains/wave ----------------
// s'[n] = fl( max_p fl(s[p]+T[p][n]) + e[n] ) — bitwise equal to ref by RNE monotonicity.
// R7/R8/R9 established cross-lane ops cost ~14 cyc ISSUE each -> 21 readlanes ≈ 290 cyc/step.
// Replace with 7 DS ops: 1 ds_write_b32 + 5 ds_read_b128 + 1 ds_read_b32 (wave-uniform
// broadcast reads; same-wave DS is in-order, no barrier). Two independent batch chains
// (separate LDS buffers) interleave so one chain's compute hides the other's DS latency.
__global__ __launch_bounds__(64) void k_scores(
    const float* __restrict__ emT, const float* __restrict__ start,
    const float* __restrict__ endt, const float* __restrict__ trans,
    float* __restrict__ sc, int* __restrict__ last_tag)
{
    __shared__ float lds[64];        // chain A: floats [0..20], chain B: [32..52]
    int n  = threadIdx.x;
    int bA = blockIdx.x * 2;
    int bB = bA + 1;

    if (n < NC) {
        const float4* erA = (const float4*)(emT + ((size_t)bA * NC + n) * L);
        const float4* erB = (const float4*)(emT + ((size_t)bB * NC + n) * L);
        float* scpA = sc + (size_t)bA * NC * L;      // 84 floats per pack
        float* scpB = sc + (size_t)bB * NC * L;

        float tc[NC];
        #pragma unroll
        for (int pp = 0; pp < NC; ++pp) tc[pp] = trans[pp*NC + n];
        #pragma unroll
        for (int pp = 0; pp < NC; ++pp) asm volatile("" : "+v"(tc[pp]));  // pin in VGPRs

        float sA[NC], sB[NC];

        #define RELOAD(S, BASE) { \
            float4 r0 = *(const float4*)(lds + (BASE));      \
            float4 r1 = *(const float4*)(lds + (BASE) + 4);  \
            float4 r2 = *(const float4*)(lds + (BASE) + 8);  \
            float4 r3 = *(const float4*)(lds + (BASE) + 12); \
            float4 r4 = *(const float4*)(lds + (BASE) + 16); \
            float  r5 = lds[(BASE) + 20];                    \
            S[0]=r0.x;  S[1]=r0.y;  S[2]=r0.z;  S[3]=r0.w;   \
            S[4]=r1.x;  S[5]=r1.y;  S[6]=r1.z;  S[7]=r1.w;   \
            S[8]=r2.x;  S[9]=r2.y;  S[10]=r2.z; S[11]=r2.w;  \
            S[12]=r3.x; S[13]=r3.y; S[14]=r3.z; S[15]=r3.w;  \
            S[16]=r4.x; S[17]=r4.y; S[18]=r4.z; S[19]=r4.w;  \
            S[20]=r5; }

        #define STEP(S, BASE, EV, OUT) { \
            float w[NC]; \
            _Pragma("unroll") \
            for (int pp = 0; pp < NC; ++pp) w[pp] = S[pp] + tc[pp];   /* fl(s+T) */ \
            float m[7]; \
            _Pragma("unroll") \
            for (int i = 0; i < 7; ++i) m[i] = fmaxf(fmaxf(w[3*i], w[3*i+1]), w[3*i+2]); \
            float a0 = fmaxf(fmaxf(m[0], m[1]), m[2]); \
            float a1 = fmaxf(fmaxf(m[3], m[4]), m[5]); \
            OUT = fmaxf(fmaxf(a0, a1), m[6]) + (EV);                  /* fl(max+e) */ \
            lds[(BASE) + n] = OUT; \
            RELOAD(S, BASE) }

        float4 eA0 = erA[0], eA1 = erA[1];
        float4 eB0 = erB[0], eB1 = erB[1];

        // ---- pack 0 (t=0 init + t=1..3), both chains ----
        float v0A = eA0.x + start[n];      // s0 = fl(em[0]+start), ref order
        float v0B = eB0.x + start[n];
        lds[n] = v0A;  lds[32 + n] = v0B;
        RELOAD(sA, 0)
        RELOAD(sB, 32)
        {
            float4 evA = eA0, evB = eB0;
            eA0 = erA[2]; eB0 = erB[2];
            float a1v, a2v, a3v, b1v, b2v, b3v;
            STEP(sA, 0,  evA.y, a1v)  STEP(sB, 32, evB.y, b1v)
            STEP(sA, 0,  evA.z, a2v)  STEP(sB, 32, evB.z, b2v)
            STEP(sA, 0,  evA.w, a3v)  STEP(sB, 32, evB.w, b3v)
            *(float4*)(scpA + n*4) = make_float4(v0A, a1v, a2v, a3v);
            *(float4*)(scpB + n*4) = make_float4(v0B, b1v, b2v, b3v);
        }

        // ---- packs 1..4095, chains interleaved ----
        for (int k = 1; k < NPACK; ++k) {
            float4 evA = (k & 1) ? eA1 : eA0;
            float4 evB = (k & 1) ? eB1 : eB0;
            int kp = k + 2; if (kp > NPACK-1) kp = NPACK-1;
            if (k & 1) { eA1 = erA[kp]; eB1 = erB[kp]; }
            else       { eA0 = erA[kp]; eB0 = erB[kp]; }

            float a0v, a1v, a2v, a3v, b0v, b1v, b2v, b3v;
            STEP(sA, 0,  evA.x, a0v)  STEP(sB, 32, evB.x, b0v)
            STEP(sA, 0,  evA.y, a1v)  STEP(sB, 32, evB.y, b1v)
            STEP(sA, 0,  evA.z, a2v)  STEP(sB, 32, evB.z, b2v)
            STEP(sA, 0,  evA.w, a3v)  STEP(sB, 32, evB.w, b3v)
            *(float4*)(scpA + k*84 + n*4) = make_float4(a0v, a1v, a2v, a3v);
            *(float4*)(scpB + k*84 + n*4) = make_float4(b0v, b1v, b2v, b3v);
        }
        #undef STEP
        #undef RELOAD

        if (n == 0) {
            float bvA = sA[0] + endt[0]; int btA = 0;
            float bvB = sB[0] + endt[0]; int btB = 0;
            #pragma unroll
            for (int j = 1; j < NC; ++j) {
                float vA = sA[j] + endt[j];
                if (vA > bvA) { bvA = vA; btA = j; }
                float vB = sB[j] + endt[j];
                if (vB > bvB) { bvB = vB; btB = j; }
            }
            last_tag[bA] = btA;
            last_tag[bB] = btB;
        }
    }
}

// ---------------- K2b: parallel backpointer recovery ----------------
// bp[t][n] = first p with fl(fl(s_{t-1}[p]+T[p][n])+e[t][n]) == s_t[n]
__global__ __launch_bounds__(256) void k_bp(
    const float* __restrict__ emT, const float* __restrict__ sc,
    const float* __restrict__ trans, uint8_t* __restrict__ bp)
{
    int wave = threadIdx.x >> 6;
    int lane = threadIdx.x & 63;
    int ne   = lane < NC ? lane : NC-1;

    int bidx  = blockIdx.x;
    int b     = bidx >> 7;                              // 128 blocks per batch
    int tbase = (bidx & 127) * (4*T_PER) + wave*T_PER;

    const float* emb = emT + (size_t)b * NC * L;
    const float* scp = sc  + (size_t)b * NC * L;
    uint8_t*     bpb = bp  + (size_t)b * L * NC;

    float tc[NC];
    #pragma unroll
    for (int pp = 0; pp < NC; ++pp) tc[pp] = trans[pp*NC + ne];

    for (int t = tbase; t < tbase + T_PER; ++t) {
        if (t == 0) continue;
        float target = scp[(t>>2)*84 + ne*4 + (t&3)];
        float e      = emb[(size_t)ne * L + t];
        const float* sp = scp + ((t-1)>>2)*84 + ((t-1)&3);
        int fi = 0;
        #pragma unroll
        for (int pp = NC-1; pp >= 0; --pp) {
            float cand = (sp[pp*4] + tc[pp]) + e;
            if (cand == target) fi = pp;
        }
        if (lane < NC) bpb[(size_t)t * NC + ne] = (uint8_t)fi;
    }
}

// ---------------- K3: chunk-parallel backtrack (integer, exact) ----------------
__global__ __launch_bounds__(64) void k_backtrack(
    const uint8_t* __restrict__ bp, const int* __restrict__ last_tag,
    int* __restrict__ out)
{
    int blk = blockIdx.x;
    int b   = blk >> 6;
    int k   = blk & (NCHUNKS-1);
    int cs  = k * CHUNK;
    int ce  = cs + CHUNK;
    int sp  = ce - 1 + WARM; if (sp > L-1) sp = L-1;
    int tag = (sp == L-1) ? last_tag[b] : 0;
    const uint8_t* bpb = bp + (size_t)b * L * NC;
    int* ob = out + (size_t)b * L;
    for (int t = sp;; --t) {
        if (t < ce) { if (threadIdx.x == 0) ob[t] = tag; }
        if (t == cs) break;
        tag = (int)bpb[(size_t)t * NC + tag];
    }
}

extern "C" void kernel_launch(void* const* d_in, const int* in_sizes, int n_in,
                              void* d_out, int out_size, void* d_ws, size_t ws_size,
                              hipStream_t stream) {
    const float* x  = (const float*)d_in[0];
    const float* w1 = (const float*)d_in[1];
    const float* b1 = (const float*)d_in[2];
    const float* w2 = (const float*)d_in[3];
    const float* b2 = (const float*)d_in[4];
    const float* st = (const float*)d_in[5];
    const float* en = (const float*)d_in[6];
    const float* tr = (const float*)d_in[7];
    int* out = (int*)d_out;

    char* ws = (char*)d_ws;
    float*   em = (float*)ws;                                    // em_T: 22,020,096 B
    float*   sc = (float*)(ws + (size_t)NB*L*NC*4);              // packed scores: 22,020,096 B
    uint8_t* bp = (uint8_t*)(ws + (size_t)NB*L*NC*8);            // 5,505,024 B
    int*     lt = (int*)(ws + (size_t)NB*L*NC*9);                // int[NB]

    k_conv     <<<dim3(NB*L/256),   dim3(256), 0, stream>>>(x, w1, b1, w2, b2, em);
    k_scores   <<<dim3(NB/2),       dim3(64),  0, stream>>>(em, st, en, tr, sc, lt);
    k_bp       <<<dim3(NB*128),     dim3(256), 0, stream>>>(em, sc, tr, bp);
    k_backtrack<<<dim3(NB*NCHUNKS), dim3(64),  0, stream>>>(bp, lt, out);
}

// Round 11
// 2642.357 us; speedup vs baseline: 1.6127x; 1.6127x over previous
//
#include <hip/hip_runtime.h>
#include <stdint.h>

#define NB 16
#define HH 128
#define WW 128
#define L (HH*WW)        // 16384
#define CIN 3
#define HID 256
#define NC 21
#define CHUNK 256
#define WARM 512
#define NCHUNKS (L/CHUNK)   // 64
#define T_PER 32            // t's per wave in k_bp
#define NPACK (L/4)         // 4096 packs of 4 timesteps

// ---------------- K1: conv -> fp32 emissions, stored TRANSPOSED em_T[b][c][t] ----------------
// fp64 accumulate (round once to fp32 = correctly rounded), fp32 elementwise bias in ref order.
__global__ __launch_bounds__(256) void k_conv(
    const float* __restrict__ x, const float* __restrict__ w1,
    const float* __restrict__ b1, const float* __restrict__ w2,
    const float* __restrict__ b2, float* __restrict__ emT)
{
    int tid = threadIdx.x;
    int g  = blockIdx.x * 256 + tid;      // 0..B*L-1
    int b  = g >> 14;
    int t  = g & (L-1);
    int y  = t >> 7;
    int xx = t & (WW-1);

    double p[27];
    const float* xb = x + (size_t)b * CIN * L;
    #pragma unroll
    for (int ic = 0; ic < CIN; ++ic) {
        #pragma unroll
        for (int ky = 0; ky < 3; ++ky) {
            #pragma unroll
            for (int kx = 0; kx < 3; ++kx) {
                int yy = y + ky - 1, xc = xx + kx - 1;
                float v = 0.f;
                if (yy >= 0 && yy < HH && xc >= 0 && xc < WW)
                    v = xb[ic * L + yy * WW + xc];
                p[ic*9 + ky*3 + kx] = (double)v;
            }
        }
    }

    double acc[NC];
    #pragma unroll
    for (int c = 0; c < NC; ++c) acc[c] = 0.0;

    // unroll 2: pipelines the wave-uniform (scalar) weight loads behind fp64 FMAs.
    // Per-accumulator FP op order unchanged -> bit-identical results.
    #pragma unroll 2
    for (int oc = 0; oc < HID; ++oc) {
        double hv = 0.0;                              // conv1 accum
        #pragma unroll
        for (int j = 0; j < 27; ++j) hv += (double)w1[oc*27 + j] * p[j];
        float h32 = (float)hv;                        // round conv1 to fp32
        h32 = h32 + b1[oc];                           // fp32 elementwise bias
        h32 = fmaxf(h32, 0.f);                        // relu (fp32)
        double hd = (double)h32;
        #pragma unroll
        for (int c = 0; c < NC; ++c) acc[c] += (double)w2[c*HID + oc] * hd;
    }
    float* dstb = emT + (size_t)b * NC * L;
    #pragma unroll
    for (int c = 0; c < NC; ++c) {
        float e32 = (float)acc[c];                    // round conv2 to fp32
        dstb[(size_t)c * L + t] = e32 + b2[c];        // transposed store (coalesced in t)
    }
}

// ---------------- K2a: sequential fp32 score recursion, p-split bpermute, 1 batch/wave ----------------
// s'[n] = fl( max_p fl(s[p]+T[p][n]) + e[n] ) — bitwise equal to ref by RNE monotonicity.
// 63 lanes = 3 p-groups x 21 states. Lane (g,n) holds ONLY s[n]. Per step:
//   7 ds_bpermute (gather s[p], p in group g; register-sourced, no LDS round-trip)
//   + 7 add + 3 max3 -> partial over 7
//   2 ds_bpermute (other groups' partials) + max3 + e-add -> s'[n] (identical in all copies)
// Cross-lane ops/step: 21 (R6 readlane) -> 9. R8/R10's "2 chains" mistake (both chains in
// lanes 0-20, doubling the instruction stream) is gone: the whole wave serves one chain.
__global__ __launch_bounds__(64) void k_scores(
    const float* __restrict__ emT, const float* __restrict__ start,
    const float* __restrict__ endt, const float* __restrict__ trans,
    float* __restrict__ sc, int* __restrict__ last_tag)
{
    __shared__ float fin[NC];
    int l = threadIdx.x;
    int b = blockIdx.x;
    int g = l / 21; if (g > 2) g = 2;        // lane 63 shadows (g=2,n=20)
    int n = l - g*21; if (n > 20) n = 20;

    const float4* er4 = (const float4*)(emT + ((size_t)b * NC + n) * L);
    float*        scp = sc + (size_t)b * NC * L;          // 84 floats per pack

    float tc[7];
    #pragma unroll
    for (int i = 0; i < 7; ++i) tc[i] = trans[(g*7 + i)*NC + n];
    #pragma unroll
    for (int i = 0; i < 7; ++i) asm volatile("" : "+v"(tc[i]));   // pin in VGPRs

    int ga[7];
    #pragma unroll
    for (int i = 0; i < 7; ++i) ga[i] = (g*7 + i) * 4;    // gather addrs (copy-0 lanes)
    #pragma unroll
    for (int i = 0; i < 7; ++i) asm volatile("" : "+v"(ga[i]));
    int g1 = g + 1; if (g1 > 2) g1 -= 3;
    int g2 = g + 2; if (g2 > 2) g2 -= 3;
    int ca1 = (n + 21*g1) * 4;                            // combine addrs (other copies)
    int ca2 = (n + 21*g2) * 4;
    asm volatile("" : "+v"(ca1), "+v"(ca2));

    float sv;   // my state's current score s[n]

    #define BPERM(A,V) __int_as_float(__builtin_amdgcn_ds_bpermute((A), __float_as_int(V)))

    #define STEP(EV, OUT) { \
        float w0 = BPERM(ga[0], sv) + tc[0]; \
        float w1 = BPERM(ga[1], sv) + tc[1]; \
        float w2 = BPERM(ga[2], sv) + tc[2]; \
        float w3 = BPERM(ga[3], sv) + tc[3]; \
        float w4 = BPERM(ga[4], sv) + tc[4]; \
        float w5 = BPERM(ga[5], sv) + tc[5]; \
        float w6 = BPERM(ga[6], sv) + tc[6]; \
        float pa = fmaxf(fmaxf(w0, w1), w2); \
        float pb = fmaxf(fmaxf(w3, w4), w5); \
        float pr = fmaxf(fmaxf(pa, pb), w6);        /* exact max over my 7 p's */ \
        float o1 = BPERM(ca1, pr); \
        float o2 = BPERM(ca2, pr); \
        OUT = fmaxf(fmaxf(pr, o1), o2) + (EV);      /* exact max over 21, then fl(+e) */ \
        sv = OUT; }

    float4 ebuf0 = er4[0];
    float4 ebuf1 = er4[1];

    // ---- pack 0 (t=0 init + t=1..3) ----
    float v0 = ebuf0.x + start[n];      // s0 = fl(em[0]+start), ref order
    sv = v0;
    {
        float4 ev = ebuf0;
        ebuf0 = er4[2];
        float a1v, a2v, a3v;
        STEP(ev.y, a1v)
        STEP(ev.z, a2v)
        STEP(ev.w, a3v)
        if (l < NC) *(float4*)(scp + n*4) = make_float4(v0, a1v, a2v, a3v);
    }

    // ---- packs 1..4095 ----
    for (int k = 1; k < NPACK; ++k) {
        float4 ev = (k & 1) ? ebuf1 : ebuf0;
        int kp = k + 2; if (kp > NPACK-1) kp = NPACK-1;
        if (k & 1) ebuf1 = er4[kp]; else ebuf0 = er4[kp];

        float b0, b1_, b2_, b3;
        STEP(ev.x, b0)
        STEP(ev.y, b1_)
        STEP(ev.z, b2_)
        STEP(ev.w, b3)
        if (l < NC) *(float4*)(scp + k*84 + n*4) = make_float4(b0, b1_, b2_, b3);
    }
    #undef STEP
    #undef BPERM

    if (l < NC) fin[n] = sv;
    __syncthreads();
    if (l == 0) {
        float bv = fin[0] + endt[0]; int bt = 0;
        #pragma unroll
        for (int j = 1; j < NC; ++j) {
            float v = fin[j] + endt[j];
            if (v > bv) { bv = v; bt = j; }
        }
        last_tag[b] = bt;
    }
}

// ---------------- K2b: parallel backpointer recovery ----------------
// bp[t][n] = first p with fl(fl(s_{t-1}[p]+T[p][n])+e[t][n]) == s_t[n]
__global__ __launch_bounds__(256) void k_bp(
    const float* __restrict__ emT, const float* __restrict__ sc,
    const float* __restrict__ trans, uint8_t* __restrict__ bp)
{
    int wave = threadIdx.x >> 6;
    int lane = threadIdx.x & 63;
    int ne   = lane < NC ? lane : NC-1;

    int bidx  = blockIdx.x;
    int b     = bidx >> 7;                              // 128 blocks per batch
    int tbase = (bidx & 127) * (4*T_PER) + wave*T_PER;

    const float* emb = emT + (size_t)b * NC * L;
    const float* scp = sc  + (size_t)b * NC * L;
    uint8_t*     bpb = bp  + (size_t)b * L * NC;

    float tc[NC];
    #pragma unroll
    for (int pp = 0; pp < NC; ++pp) tc[pp] = trans[pp*NC + ne];

    for (int t = tbase; t < tbase + T_PER; ++t) {
        if (t == 0) continue;
        float target = scp[(t>>2)*84 + ne*4 + (t&3)];
        float e      = emb[(size_t)ne * L + t];
        const float* sp = scp + ((t-1)>>2)*84 + ((t-1)&3);
        int fi = 0;
        #pragma unroll
        for (int pp = NC-1; pp >= 0; --pp) {
            float cand = (sp[pp*4] + tc[pp]) + e;
            if (cand == target) fi = pp;
        }
        if (lane < NC) bpb[(size_t)t * NC + ne] = (uint8_t)fi;
    }
}

// ---------------- K3: chunk-parallel backtrack (integer, exact) ----------------
__global__ __launch_bounds__(64) void k_backtrack(
    const uint8_t* __restrict__ bp, const int* __restrict__ last_tag,
    int* __restrict__ out)
{
    int blk = blockIdx.x;
    int b   = blk >> 6;
    int k   = blk & (NCHUNKS-1);
    int cs  = k * CHUNK;
    int ce  = cs + CHUNK;
    int sp  = ce - 1 + WARM; if (sp > L-1) sp = L-1;
    int tag = (sp == L-1) ? last_tag[b] : 0;
    const uint8_t* bpb = bp + (size_t)b * L * NC;
    int* ob = out + (size_t)b * L;
    for (int t = sp;; --t) {
        if (t < ce) { if (threadIdx.x == 0) ob[t] = tag; }
        if (t == cs) break;
        tag = (int)bpb[(size_t)t * NC + tag];
    }
}

extern "C" void kernel_launch(void* const* d_in, const int* in_sizes, int n_in,
                              void* d_out, int out_size, void* d_ws, size_t ws_size,
                              hipStream_t stream) {
    const float* x  = (const float*)d_in[0];
    const float* w1 = (const float*)d_in[1];
    const float* b1 = (const float*)d_in[2];
    const float* w2 = (const float*)d_in[3];
    const float* b2 = (const float*)d_in[4];
    const float* st = (const float*)d_in[5];
    const float* en = (const float*)d_in[6];
    const float* tr = (const float*)d_in[7];
    int* out = (int*)d_out;

    char* ws = (char*)d_ws;
    float*   em = (float*)ws;                                    // em_T: 22,020,096 B
    float*   sc = (float*)(ws + (size_t)NB*L*NC*4);              // packed scores: 22,020,096 B
    uint8_t* bp = (uint8_t*)(ws + (size_t)NB*L*NC*8);            // 5,505,024 B
    int*     lt = (int*)(ws + (size_t)NB*L*NC*9);                // int[NB]

    k_conv     <<<dim3(NB*L/256),   dim3(256), 0, stream>>>(x, w1, b1, w2, b2, em);
    k_scores   <<<dim3(NB),         dim3(64),  0, stream>>>(em, st, en, tr, sc, lt);
    k_bp       <<<dim3(NB*128),     dim3(256), 0, stream>>>(em, sc, tr, bp);
    k_backtrack<<<dim3(NB*NCHUNKS), dim3(64),  0, stream>>>(bp, lt, out);
}